// Round 5
// baseline (150.491 us; speedup 1.0000x reference)
//
#include <hip/hip_runtime.h>

// CRF forward (logZ) — B=1024 chains, T=256 steps, N=64 labels.
// One 64-lane wave per chain; lane k owns label k.
// Wall time = 256 x per-step critical latency (waves are free: 1024 SIMDs).
// HYBRID broadcast per step, two parallel pipes:
//   front half (u_0..u_31):  pack_pairs (DPP) + 16 v_readlane -> 16 dot2
//   back  half (u_32..u_63): ds_write_b16 at step start, 4x ds_read_b128
//                            (~120cy latency hidden under the front half)
// Both halves use identical bf16 rounding ((bits+0x8000)>>16) — each was
// separately verified (baseline readlane kernel, R4 LDS kernel; absmax 0).
// 8 accumulators -> 4-deep dot2 chains. Per-group exp/load tail is rotated
// into each step body to fill the LDS-latency shadow.
// Exact lse recursion with per-step scaling: u_k(t)=s_k*(R*ee_k), R=rcp(u0),
// Pm *= u0 with u0 = rl0(s)*R*ee0 (off the broadcast critical path).

#define CRF_B 1024
#define CRF_T 256
#define CRF_N 64

typedef __bf16 bf16x2 __attribute__((ext_vector_type(2)));

__device__ __forceinline__ float rl0(float x) {
    return __int_as_float(__builtin_amdgcn_readfirstlane(__float_as_int(x)));
}
__device__ __forceinline__ float rlanef(float x, int j) {
    return __int_as_float(__builtin_amdgcn_readlane(__float_as_int(x), j));
}

__device__ __forceinline__ float wave_lse(float v) {
    float m = v;
    #pragma unroll
    for (int off = 1; off < 64; off <<= 1) m = fmaxf(m, __shfl_xor(m, off));
    float s = __expf(v - m);
    #pragma unroll
    for (int off = 1; off < 64; off <<= 1) s += __shfl_xor(s, off);
    return m + __logf(s);
}

// f32 -> bf16 (round-to-nearest-even), low 16 bits of result
__device__ __forceinline__ unsigned bf16_rne(float f) {
    unsigned u = __float_as_uint(f);
    return (u + 0x7FFFu + ((u >> 16) & 1u)) >> 16;
}

// lane L: pack(bf16(u_L), bf16(u_{L^1})) — valid pairs read from EVEN lanes
__device__ __forceinline__ unsigned pack_pairs(float u) {
    unsigned pa = __float_as_uint(u) + 0x8000u;                 // cheap RN
    unsigned pb = (unsigned)__builtin_amdgcn_update_dpp(
        0, (int)pa, 0xB1 /*quad_perm [1,0,3,2]*/, 0xF, 0xF, false);
    // result: lo16 = pa[31:16], hi16 = pb[31:16]
    return __builtin_amdgcn_perm(pb, pa, 0x07060302);
}

__device__ __forceinline__ float dot2bf(unsigned a, unsigned b, float c) {
#if __has_builtin(__builtin_amdgcn_fdot2_f32_bf16)
    return __builtin_amdgcn_fdot2_f32_bf16(__builtin_bit_cast(bf16x2, a),
                                           __builtin_bit_cast(bf16x2, b),
                                           c, false);
#else
    float d = c;
    asm("v_dot2_f32_bf16 %0, %1, %2, %0" : "+v"(d) : "v"(a), "v"(b));
    return d;
#endif
}

__launch_bounds__(64, 1)
__global__ void crf_fwd_kernel(const float* __restrict__ emit,
                               const float* __restrict__ trans,
                               const float* __restrict__ strans,
                               const float* __restrict__ etrans,
                               const unsigned char* __restrict__ mask_u8,
                               float* __restrict__ out)
{
    const int lane = threadIdx.x;   // 0..63
    const int b    = blockIdx.x;

    // 64 bf16 u-values, packed as 32 dwords of (u_2m, u_2m+1) pairs.
    // Only dwords 16..31 (u_32..u_63) are read (back half); front half
    // is served by readlane.
    __shared__ __attribute__((aligned(16))) unsigned s_up[32];

    // ---------- register-only preprocess (per wave) ----------
    float rowlse_v;
    {
        const float* rowp = trans + lane * CRF_N;
        float m = -1e30f;
        #pragma unroll 8
        for (int k = 0; k < CRF_N; ++k) m = fmaxf(m, rowp[k]);
        float s = 0.f;
        #pragma unroll 8
        for (int k = 0; k < CRF_N; ++k) s += __expf(rowp[k] - m);
        rowlse_v = m + __logf(s);
    }

    // pass 1: column max of tn (for this lane's label)
    float cmx = -1e30f;
    #pragma unroll
    for (int j = 0; j < CRF_N; ++j)
        cmx = fmaxf(cmx, trans[j * CRF_N + lane] - rlanef(rowlse_v, j));

    // pass 2: packed bf16 E pairs — Epk[m] = (E[2m][lane], E[2m+1][lane])
    unsigned Epk[32];
    #pragma unroll
    for (int m = 0; m < 32; ++m) {
        float e0 = __expf(trans[(2 * m)     * CRF_N + lane] - rlanef(rowlse_v, 2 * m)     - cmx);
        float e1 = __expf(trans[(2 * m + 1) * CRF_N + lane] - rlanef(rowlse_v, 2 * m + 1) - cmx);
        Epk[m] = bf16_rne(e0) | (bf16_rne(e1) << 16);
    }

    const float sn = wave_lse(strans[lane]);

    // ---- sequence length from mask (dtype-adaptive: bool bytes vs int32) ----
    int len;
    {
        int c8 = 0;
        #pragma unroll
        for (int q = 0; q < 4; ++q)
            c8 += (mask_u8[(size_t)b * CRF_T + q * 64 + lane] != 0) ? 1 : 0;
        for (int off = 1; off < 64; off <<= 1) c8 += __shfl_xor(c8, off);
        if (c8 >= 128) {
            len = c8;       // genuine bool bytes (len in [128,256])
        } else {
            const int* mi = (const int*)mask_u8;
            int ci = 0;
            #pragma unroll
            for (int q = 0; q < 4; ++q)
                ci += (mi[(size_t)b * CRF_T + q * 64 + lane] != 0) ? 1 : 0;
            for (int off = 1; off < 64; off <<= 1) ci += __shfl_xor(ci, off);
            len = ci;
        }
    }

    const float* eb = emit + (size_t)b * CRF_T * CRF_N;

    // ---------- init (t = 0) ----------
    float alpha0 = (strans[lane] - sn) + eb[lane];
    float c0 = rl0(alpha0);
    float u  = __expf(alpha0 - c0);   // lane 0: u = 1
    // publish bf16(u) for the first step's back-half broadcast
    ((unsigned short*)s_up)[lane] =
        (unsigned short)((__float_as_uint(u) + 0x8000u) >> 16);
    float R  = 1.0f;                  // rcp of previous step's u0
    float Pm = 1.0f;                  // running product of u0 (mantissa)
    int   Eacc = 0;                   // running exponent (base 2)

    // one step: hybrid broadcast (readlane front / LDS back), 8 accs 4-deep
#define CRF_STEP(EE, EE0)                                                   \
    {                                                                       \
        float ree = R * (EE);         /* ready before dots complete */      \
        float sc0 = R * (EE0);                                              \
        /* publish u for the back half FIRST (start LDS latency clock) */   \
        ((unsigned short*)s_up)[lane] =                                     \
            (unsigned short)((__float_as_uint(u) + 0x8000u) >> 16);         \
        unsigned upi_ = pack_pairs(u);                                      \
        /* back-half reads: dwords 16..31 (u_32..u_63) */                   \
        uint4 w4 = *(const uint4*)&s_up[16];                                \
        uint4 w5 = *(const uint4*)&s_up[20];                                \
        uint4 w6 = *(const uint4*)&s_up[24];                                \
        uint4 w7 = *(const uint4*)&s_up[28];                                \
        float a0 = 0.f, a1 = 0.f, a2 = 0.f, a3 = 0.f;                       \
        float a4 = 0.f, a5 = 0.f, a6 = 0.f, a7 = 0.f;                       \
        /* front half via readlane: m = 0..15 */                            \
        a0 = dot2bf((unsigned)__builtin_amdgcn_readlane((int)upi_,  0), Epk[ 0], a0); \
        a1 = dot2bf((unsigned)__builtin_amdgcn_readlane((int)upi_,  2), Epk[ 1], a1); \
        a2 = dot2bf((unsigned)__builtin_amdgcn_readlane((int)upi_,  4), Epk[ 2], a2); \
        a3 = dot2bf((unsigned)__builtin_amdgcn_readlane((int)upi_,  6), Epk[ 3], a3); \
        a4 = dot2bf((unsigned)__builtin_amdgcn_readlane((int)upi_,  8), Epk[ 4], a4); \
        a5 = dot2bf((unsigned)__builtin_amdgcn_readlane((int)upi_, 10), Epk[ 5], a5); \
        a6 = dot2bf((unsigned)__builtin_amdgcn_readlane((int)upi_, 12), Epk[ 6], a6); \
        a7 = dot2bf((unsigned)__builtin_amdgcn_readlane((int)upi_, 14), Epk[ 7], a7); \
        a0 = dot2bf((unsigned)__builtin_amdgcn_readlane((int)upi_, 16), Epk[ 8], a0); \
        a1 = dot2bf((unsigned)__builtin_amdgcn_readlane((int)upi_, 18), Epk[ 9], a1); \
        a2 = dot2bf((unsigned)__builtin_amdgcn_readlane((int)upi_, 20), Epk[10], a2); \
        a3 = dot2bf((unsigned)__builtin_amdgcn_readlane((int)upi_, 22), Epk[11], a3); \
        a4 = dot2bf((unsigned)__builtin_amdgcn_readlane((int)upi_, 24), Epk[12], a4); \
        a5 = dot2bf((unsigned)__builtin_amdgcn_readlane((int)upi_, 26), Epk[13], a5); \
        a6 = dot2bf((unsigned)__builtin_amdgcn_readlane((int)upi_, 28), Epk[14], a6); \
        a7 = dot2bf((unsigned)__builtin_amdgcn_readlane((int)upi_, 30), Epk[15], a7); \
        /* back half from LDS: m = 16..31 (arrived during front half) */    \
        a0 = dot2bf(w4.x, Epk[16], a0);                                     \
        a1 = dot2bf(w4.y, Epk[17], a1);                                     \
        a2 = dot2bf(w4.z, Epk[18], a2);                                     \
        a3 = dot2bf(w4.w, Epk[19], a3);                                     \
        a4 = dot2bf(w5.x, Epk[20], a4);                                     \
        a5 = dot2bf(w5.y, Epk[21], a5);                                     \
        a6 = dot2bf(w5.z, Epk[22], a6);                                     \
        a7 = dot2bf(w5.w, Epk[23], a7);                                     \
        a0 = dot2bf(w6.x, Epk[24], a0);                                     \
        a1 = dot2bf(w6.y, Epk[25], a1);                                     \
        a2 = dot2bf(w6.z, Epk[26], a2);                                     \
        a3 = dot2bf(w6.w, Epk[27], a3);                                     \
        a4 = dot2bf(w7.x, Epk[28], a4);                                     \
        a5 = dot2bf(w7.y, Epk[29], a5);                                     \
        a6 = dot2bf(w7.z, Epk[30], a6);                                     \
        a7 = dot2bf(w7.w, Epk[31], a7);                                     \
        float s = (((a0 + a1) + (a2 + a3)) + ((a4 + a5) + (a6 + a7)));      \
        float s0 = rl0(s);                                                  \
        u = s * ree;                                                        \
        float u0 = s0 * sc0;          /* == lane-0 of u (assoc. diff) */    \
        R = __builtin_amdgcn_rcpf(u0);                                      \
        Pm *= u0;                                                           \
    }

    // rotation: refresh ee slot d (for step t0+4+d) and preload t0+8+d.
    // Placed right after STEP(d) so the exp/rl0/load issue into the LDS
    // shadow of the following step instead of serializing at group end.
#define CRF_ROT(D)                                                          \
    {                                                                       \
        eeC[D]  = __expf(eN[D] + cmx);                                      \
        ee0C[D] = rl0(eeC[D]);                                              \
        int ti = t0 + 8 + (D);                                              \
        ti = (ti < len) ? ti : (len - 1);                                   \
        eN[D] = eb[(size_t)ti * CRF_N + lane];                              \
    }

    // ---------- main loop ----------
    float eN[4], eeC[4], ee0C[4];
    #pragma unroll
    for (int d = 0; d < 4; ++d) eN[d] = eb[(size_t)(1 + d) * CRF_N + lane];
    #pragma unroll
    for (int d = 0; d < 4; ++d) eeC[d] = __expf(eN[d] + cmx);
    #pragma unroll
    for (int d = 0; d < 4; ++d) ee0C[d] = rl0(eeC[d]);
    #pragma unroll
    for (int d = 0; d < 4; ++d) eN[d] = eb[(size_t)(5 + d) * CRF_N + lane];

    int t0 = 1;
    while (t0 + 4 <= len) {
        CRF_STEP(eeC[0], ee0C[0]); CRF_ROT(0);
        CRF_STEP(eeC[1], ee0C[1]); CRF_ROT(1);
        CRF_STEP(eeC[2], ee0C[2]); CRF_ROT(2);
        CRF_STEP(eeC[3], ee0C[3]); CRF_ROT(3);
        {
            int ex;
            Pm = frexpf(Pm, &ex);
            Eacc += ex;
        }
        t0 += 4;
    }
    {
        const int nrem = len - t0;   // wave-uniform, < 4
        #pragma unroll
        for (int d = 0; d < 4; ++d) {
            if (d >= nrem) break;
            CRF_STEP(eeC[d], ee0C[d]);
        }
    }
#undef CRF_STEP
#undef CRF_ROT

    // ---------- final lse over labels + batch-sum ----------
    const float en = wave_lse(etrans[lane]);
    float Lacc = c0 + 0.6931471805599453f * (float)Eacc + __logf(Pm);
    float v = Lacc + __logf(u * R) + (etrans[lane] - en);
    float m = v;
    #pragma unroll
    for (int off = 1; off < 64; off <<= 1) m = fmaxf(m, __shfl_xor(m, off));
    float sum = __expf(v - m);
    #pragma unroll
    for (int off = 1; off < 64; off <<= 1) sum += __shfl_xor(sum, off);

    if (lane == 0) {
        atomicAdd(out, m + __logf(sum));
    }
}

extern "C" void kernel_launch(void* const* d_in, const int* in_sizes, int n_in,
                              void* d_out, int out_size, void* d_ws, size_t ws_size,
                              hipStream_t stream) {
    const float* emit   = (const float*)d_in[0];
    const float* trans  = (const float*)d_in[1];
    const float* strans = (const float*)d_in[2];
    const float* etrans = (const float*)d_in[3];
    const unsigned char* mask = (const unsigned char*)d_in[4];
    float* out = (float*)d_out;

    hipMemsetAsync(out, 0, sizeof(float), stream);
    crf_fwd_kernel<<<dim3(CRF_B), dim3(64), 0, stream>>>(
        emit, trans, strans, etrans, mask, out);
}

// Round 6
// 147.530 us; speedup vs baseline: 1.0201x; 1.0201x over previous
//
#include <hip/hip_runtime.h>

// CRF forward (logZ) — B=1024 chains, T=256 steps, N=64 labels.
// One 64-lane wave per chain; lane k owns label k.
// Wall time = 256 x per-step latency (waves are free: 1024 SIMDs, 1/SIMD).
// Cost model fitted over 5 rounds: v_readlane ~12cy issue; LDS b128-broadcast
// round trip ~220cy; dot2 cheap. Hybrid step, schedule pinned by inline asm:
//   t start: asm{ ds_write_b16 u ; 4x ds_read_b128 (u_32..u_63) }  (issue only)
//   front:   pack_pairs + 16 readlane -> 16 dot2  (~210cy, covers LDS latency)
//   asm{ s_waitcnt lgkmcnt(0) } + sched_barrier(0)   <- rule #18: compiler
//        cannot hoist this wait (R5 regression: hipcc hoisted the implicit
//        wait above the front half when reads were plain C loads)
//   back:    16 dot2 from the LDS words.
// Identical bf16 rounding everywhere ((bits+0x8000)>>16) — the verified scheme
// (baseline readlane kernel and R4 LDS kernel both absmax 0).
// Exact lse recursion with per-step scaling: u_k(t)=s_k*(R*ee_k), R=rcp(u0),
// Pm *= u0 with u0 = rl0(s)*R*ee0 (off the broadcast critical path).

#define CRF_B 1024
#define CRF_T 256
#define CRF_N 64

typedef __bf16 bf16x2 __attribute__((ext_vector_type(2)));

__device__ __forceinline__ float rl0(float x) {
    return __int_as_float(__builtin_amdgcn_readfirstlane(__float_as_int(x)));
}
__device__ __forceinline__ float rlanef(float x, int j) {
    return __int_as_float(__builtin_amdgcn_readlane(__float_as_int(x), j));
}

__device__ __forceinline__ float wave_lse(float v) {
    float m = v;
    #pragma unroll
    for (int off = 1; off < 64; off <<= 1) m = fmaxf(m, __shfl_xor(m, off));
    float s = __expf(v - m);
    #pragma unroll
    for (int off = 1; off < 64; off <<= 1) s += __shfl_xor(s, off);
    return m + __logf(s);
}

// f32 -> bf16 (round-to-nearest-even), low 16 bits of result
__device__ __forceinline__ unsigned bf16_rne(float f) {
    unsigned u = __float_as_uint(f);
    return (u + 0x7FFFu + ((u >> 16) & 1u)) >> 16;
}

// from pa = bits(u)+0x8000: lane L gets pack(bf16(u_L), bf16(u_{L^1}))
// (valid pairs read from EVEN lanes)
__device__ __forceinline__ unsigned pack_pairs_pa(unsigned pa) {
    unsigned pb = (unsigned)__builtin_amdgcn_update_dpp(
        0, (int)pa, 0xB1 /*quad_perm [1,0,3,2]*/, 0xF, 0xF, false);
    // result: lo16 = pa[31:16], hi16 = pb[31:16]
    return __builtin_amdgcn_perm(pb, pa, 0x07060302);
}

__device__ __forceinline__ float dot2bf(unsigned a, unsigned b, float c) {
#if __has_builtin(__builtin_amdgcn_fdot2_f32_bf16)
    return __builtin_amdgcn_fdot2_f32_bf16(__builtin_bit_cast(bf16x2, a),
                                           __builtin_bit_cast(bf16x2, b),
                                           c, false);
#else
    float d = c;
    asm("v_dot2_f32_bf16 %0, %1, %2, %0" : "+v"(d) : "v"(a), "v"(b));
    return d;
#endif
}

__launch_bounds__(64, 1)
__global__ void crf_fwd_kernel(const float* __restrict__ emit,
                               const float* __restrict__ trans,
                               const float* __restrict__ strans,
                               const float* __restrict__ etrans,
                               const unsigned char* __restrict__ mask_u8,
                               float* __restrict__ out)
{
    const int lane = threadIdx.x;   // 0..63
    const int b    = blockIdx.x;

    // 64 bf16 u-values, packed as 32 dwords of (u_2m, u_2m+1) pairs.
    // Step reads only dwords 16..31 (u_32..u_63); front half via readlane.
    __shared__ __attribute__((aligned(16))) unsigned s_up[32];

    // raw 32-bit LDS addresses for inline-asm DS ops
    // (low 32 bits of the generic shared pointer == LDS byte offset)
    const unsigned lds_base = (unsigned)(unsigned long long)(&s_up[0]);
    const unsigned lds_wr   = lds_base + (unsigned)lane * 2u;
    const unsigned lds_rd   = lds_base + 64u;   // dword 16

    // ---------- register-only preprocess (per wave) ----------
    float rowlse_v;
    {
        const float* rowp = trans + lane * CRF_N;
        float m = -1e30f;
        #pragma unroll 8
        for (int k = 0; k < CRF_N; ++k) m = fmaxf(m, rowp[k]);
        float s = 0.f;
        #pragma unroll 8
        for (int k = 0; k < CRF_N; ++k) s += __expf(rowp[k] - m);
        rowlse_v = m + __logf(s);
    }

    // pass 1: column max of tn (for this lane's label)
    float cmx = -1e30f;
    #pragma unroll
    for (int j = 0; j < CRF_N; ++j)
        cmx = fmaxf(cmx, trans[j * CRF_N + lane] - rlanef(rowlse_v, j));

    // pass 2: packed bf16 E pairs — Epk[m] = (E[2m][lane], E[2m+1][lane])
    unsigned Epk[32];
    #pragma unroll
    for (int m = 0; m < 32; ++m) {
        float e0 = __expf(trans[(2 * m)     * CRF_N + lane] - rlanef(rowlse_v, 2 * m)     - cmx);
        float e1 = __expf(trans[(2 * m + 1) * CRF_N + lane] - rlanef(rowlse_v, 2 * m + 1) - cmx);
        Epk[m] = bf16_rne(e0) | (bf16_rne(e1) << 16);
    }

    const float sn = wave_lse(strans[lane]);

    // ---- sequence length from mask (dtype-adaptive: bool bytes vs int32) ----
    int len;
    {
        int c8 = 0;
        #pragma unroll
        for (int q = 0; q < 4; ++q)
            c8 += (mask_u8[(size_t)b * CRF_T + q * 64 + lane] != 0) ? 1 : 0;
        for (int off = 1; off < 64; off <<= 1) c8 += __shfl_xor(c8, off);
        if (c8 >= 128) {
            len = c8;       // genuine bool bytes (len in [128,256])
        } else {
            const int* mi = (const int*)mask_u8;
            int ci = 0;
            #pragma unroll
            for (int q = 0; q < 4; ++q)
                ci += (mi[(size_t)b * CRF_T + q * 64 + lane] != 0) ? 1 : 0;
            for (int off = 1; off < 64; off <<= 1) ci += __shfl_xor(ci, off);
            len = ci;
        }
    }

    const float* eb = emit + (size_t)b * CRF_T * CRF_N;

    // ---------- init (t = 0) ----------
    float alpha0 = (strans[lane] - sn) + eb[lane];
    float c0 = rl0(alpha0);
    float u  = __expf(alpha0 - c0);   // lane 0: u = 1
    float R  = 1.0f;                  // rcp of previous step's u0
    float Pm = 1.0f;                  // running product of u0 (mantissa)
    int   Eacc = 0;                   // running exponent (base 2)
    // (no init LDS write needed: each step publishes current u before reading)

    // one step: asm-paced hybrid broadcast (readlane front / LDS back)
#define CRF_STEP(EE, EE0)                                                   \
    {                                                                       \
        float ree = R * (EE);         /* ready before dots complete */      \
        float sc0 = R * (EE0);                                              \
        unsigned pa_ = __float_as_uint(u) + 0x8000u;                        \
        uint4 w4, w5, w6, w7;                                               \
        asm volatile(                                                       \
            "ds_write_b16 %5, %6\n\t"                                       \
            "ds_read_b128 %0, %4 offset:0\n\t"                              \
            "ds_read_b128 %1, %4 offset:16\n\t"                             \
            "ds_read_b128 %2, %4 offset:32\n\t"                             \
            "ds_read_b128 %3, %4 offset:48"                                 \
            : "=&v"(w4), "=&v"(w5), "=&v"(w6), "=&v"(w7)                    \
            : "v"(lds_rd), "v"(lds_wr), "v"(pa_ >> 16)                      \
            : "memory");                                                    \
        unsigned upi_ = pack_pairs_pa(pa_);                                 \
        float a0 = 0.f, a1 = 0.f, a2 = 0.f, a3 = 0.f;                       \
        float a4 = 0.f, a5 = 0.f, a6 = 0.f, a7 = 0.f;                       \
        /* front half via readlane: u_0..u_31 -> Epk[0..15] */              \
        _Pragma("unroll")                                                   \
        for (int m2 = 0; m2 < 16; m2 += 4) {                                \
            unsigned q0 = (unsigned)__builtin_amdgcn_readlane((int)upi_, 2 * m2 + 0); \
            unsigned q1 = (unsigned)__builtin_amdgcn_readlane((int)upi_, 2 * m2 + 2); \
            unsigned q2 = (unsigned)__builtin_amdgcn_readlane((int)upi_, 2 * m2 + 4); \
            unsigned q3 = (unsigned)__builtin_amdgcn_readlane((int)upi_, 2 * m2 + 6); \
            a0 = dot2bf(q0, Epk[m2 + 0], a0);                               \
            a1 = dot2bf(q1, Epk[m2 + 1], a1);                               \
            a2 = dot2bf(q2, Epk[m2 + 2], a2);                               \
            a3 = dot2bf(q3, Epk[m2 + 3], a3);                               \
        }                                                                   \
        /* LDS data has arrived under the front half; pin the wait HERE */  \
        asm volatile("s_waitcnt lgkmcnt(0)" ::: "memory");                  \
        __builtin_amdgcn_sched_barrier(0);                                  \
        /* back half from LDS: u_32..u_63 -> Epk[16..31] */                 \
        a4 = dot2bf(w4.x, Epk[16], a4);                                     \
        a5 = dot2bf(w4.y, Epk[17], a5);                                     \
        a6 = dot2bf(w4.z, Epk[18], a6);                                     \
        a7 = dot2bf(w4.w, Epk[19], a7);                                     \
        a4 = dot2bf(w5.x, Epk[20], a4);                                     \
        a5 = dot2bf(w5.y, Epk[21], a5);                                     \
        a6 = dot2bf(w5.z, Epk[22], a6);                                     \
        a7 = dot2bf(w5.w, Epk[23], a7);                                     \
        a4 = dot2bf(w6.x, Epk[24], a4);                                     \
        a5 = dot2bf(w6.y, Epk[25], a5);                                     \
        a6 = dot2bf(w6.z, Epk[26], a6);                                     \
        a7 = dot2bf(w6.w, Epk[27], a7);                                     \
        a4 = dot2bf(w7.x, Epk[28], a4);                                     \
        a5 = dot2bf(w7.y, Epk[29], a5);                                     \
        a6 = dot2bf(w7.z, Epk[30], a6);                                     \
        a7 = dot2bf(w7.w, Epk[31], a7);                                     \
        float s = (((a0 + a1) + (a2 + a3)) + ((a4 + a5) + (a6 + a7)));      \
        float s0 = rl0(s);                                                  \
        u = s * ree;                                                        \
        float u0 = s0 * sc0;          /* == lane-0 of u (assoc. diff) */    \
        R = __builtin_amdgcn_rcpf(u0);                                      \
        Pm *= u0;                                                           \
    }

    // ---------- main loop: groups of 4 with emission prefetch (R4 shape) ----
    float eN[4], eeC[4], ee0C[4];
    #pragma unroll
    for (int d = 0; d < 4; ++d) eN[d] = eb[(size_t)(1 + d) * CRF_N + lane];
    #pragma unroll
    for (int d = 0; d < 4; ++d) eeC[d] = __expf(eN[d] + cmx);
    #pragma unroll
    for (int d = 0; d < 4; ++d) ee0C[d] = rl0(eeC[d]);

    int t0 = 1;
    while (t0 + 4 <= len) {
        #pragma unroll
        for (int d = 0; d < 4; ++d) {
            int ti = t0 + 4 + d;
            ti = (ti < len) ? ti : (len - 1);
            eN[d] = eb[(size_t)ti * CRF_N + lane];
        }
        CRF_STEP(eeC[0], ee0C[0]); CRF_STEP(eeC[1], ee0C[1]);
        CRF_STEP(eeC[2], ee0C[2]); CRF_STEP(eeC[3], ee0C[3]);
        {
            int ex;
            Pm = frexpf(Pm, &ex);
            Eacc += ex;
        }
        #pragma unroll
        for (int d = 0; d < 4; ++d) eeC[d] = __expf(eN[d] + cmx);
        #pragma unroll
        for (int d = 0; d < 4; ++d) ee0C[d] = rl0(eeC[d]);
        t0 += 4;
    }
    {
        const int nrem = len - t0;   // wave-uniform, < 4
        #pragma unroll
        for (int d = 0; d < 4; ++d) {
            if (d >= nrem) break;
            CRF_STEP(eeC[d], ee0C[d]);
        }
    }
#undef CRF_STEP

    // ---------- final lse over labels + batch-sum ----------
    const float en = wave_lse(etrans[lane]);
    float Lacc = c0 + 0.6931471805599453f * (float)Eacc + __logf(Pm);
    float v = Lacc + __logf(u * R) + (etrans[lane] - en);
    float m = v;
    #pragma unroll
    for (int off = 1; off < 64; off <<= 1) m = fmaxf(m, __shfl_xor(m, off));
    float sum = __expf(v - m);
    #pragma unroll
    for (int off = 1; off < 64; off <<= 1) sum += __shfl_xor(sum, off);

    if (lane == 0) {
        atomicAdd(out, m + __logf(sum));
    }
}

extern "C" void kernel_launch(void* const* d_in, const int* in_sizes, int n_in,
                              void* d_out, int out_size, void* d_ws, size_t ws_size,
                              hipStream_t stream) {
    const float* emit   = (const float*)d_in[0];
    const float* trans  = (const float*)d_in[1];
    const float* strans = (const float*)d_in[2];
    const float* etrans = (const float*)d_in[3];
    const unsigned char* mask = (const unsigned char*)d_in[4];
    float* out = (float*)d_out;

    hipMemsetAsync(out, 0, sizeof(float), stream);
    crf_fwd_kernel<<<dim3(CRF_B), dim3(64), 0, stream>>>(
        emit, trans, strans, etrans, mask, out);
}